// Round 17
// baseline (299.289 us; speedup 1.0000x reference)
//
#include <hip/hip_runtime.h>
#include <hip/hip_bf16.h>
#include <stdint.h>

#define M_DIM 8192
#define N_DIM 4096
#define K_DIM 4096
#define R_DIM 32
#define KPAD  4160   // 4096 quant cols + 32 lora cols + 32 zero pad = 65 * 64
#define NT    65     // K-tiles of 64
#define QMAXF 7.0f

using bf16_t = __hip_bfloat16;
typedef __attribute__((ext_vector_type(4))) float f32x4;
typedef __attribute__((ext_vector_type(8))) short bf16x8;

// ---------------------------------------------------------------------------
// async global->LDS 16B stage (LDS dest = wave-uniform base + lane*16)
// ---------------------------------------------------------------------------
__device__ __forceinline__ void stage16(const void* g, void* l) {
#if defined(__has_builtin) && __has_builtin(__builtin_amdgcn_global_load_lds)
  __builtin_amdgcn_global_load_lds(
      (const __attribute__((address_space(1))) unsigned int*)g,
      (__attribute__((address_space(3))) unsigned int*)l, 16, 0, 0);
#else
  *(uint4*)l = *(const uint4*)g;
#endif
}

// ---------------------------------------------------------------------------
// ldT kernel (tiny, runs first): lora_down [K][R] -> bf16 ldT [R][K].
// Only 16 blocks; it is the sole dependency of fused_x, so isolating it
// lets quant_w overlap with fused_x in the next launch.
// ---------------------------------------------------------------------------
__global__ __launch_bounds__(256) void ldT_kernel(
    const float* __restrict__ ld, bf16_t* __restrict__ ldT) {
  const int k = blockIdx.x * 256 + threadIdx.x;
  float v[R_DIM];
#pragma unroll
  for (int i = 0; i < R_DIM / 4; ++i) {
    float4 a = *(const float4*)(ld + (size_t)k * R_DIM + i * 4);
    v[i*4+0] = a.x; v[i*4+1] = a.y; v[i*4+2] = a.z; v[i*4+3] = a.w;
  }
#pragma unroll
  for (int r = 0; r < R_DIM; ++r)
    ldT[(size_t)r * K_DIM + k] = __float2bfloat16(v[r]);
}

// ---------------------------------------------------------------------------
// prep_all kernel: block-range dispatch merging the two independent
// memory-bound jobs so they share the chip (round-17: was 2 serialized
// launches totalling ~60 us; combined traffic ~304 MB @ ~5.3 TB/s ~ 57 us).
//   blocks [0, 512)     : fused_x  (heavy blocks first for tail-filling)
//   blocks [512, 4608)  : quant_w  (independent of ldT)
//
// fused_x: SINGLE pass over x does BOTH
//   (a) smooth + per-group(64) int4 fake-quant -> Ap cols 0..4095 (+ pad)
//   (b) t = xs @ lora_down (both 16-col halves) -> Ap cols 4096..4127
// Block = 16 x-rows, 256 threads; wave w owns k-quarter [w*1024,(w+1)*1024).
// quant_w: fake-quant -> Bp cols 0..4095, lora_up -> 4096..4127, pad.
// ---------------------------------------------------------------------------
__global__ __launch_bounds__(256) void prep_all_kernel(
    const float* __restrict__ x, const float* __restrict__ smooth,
    const float* __restrict__ w, const float* __restrict__ lora_up,
    const bf16_t* __restrict__ ldT,
    bf16_t* __restrict__ Ap, bf16_t* __restrict__ Bp) {
  const int bid = blockIdx.x;
  const int tid = threadIdx.x;

  if (bid < 512) {                         // ---- fused_x ----
    __shared__ float tpart[3][16][32];

    const int w    = tid >> 6;      // k-quarter 0..3
    const int lane = tid & 63;
    const int r    = lane & 15;     // x row within block
    const int kg   = lane >> 4;     // k-granule 0..3
    const int m0   = bid * 16;
    const int mrow = m0 + r;

    const float*  xr  = x + (size_t)mrow * K_DIM;
    const bf16_t* br0 = ldT + (size_t)r * K_DIM;          // col tile 0: n = r
    const bf16_t* br1 = ldT + (size_t)(16 + r) * K_DIM;   // col tile 1: n = 16+r

    f32x4 acc0 = {0.f, 0.f, 0.f, 0.f};
    f32x4 acc1 = {0.f, 0.f, 0.f, 0.f};
    const int kbase = w * 1024;

    for (int s = 0; s < 32; s += 2) {
      const int ke = kbase + s * 32 + kg * 8;   // even step
      const int ko = ke + 32;                   // odd step

      float v[16];
      union { bf16_t h[8]; bf16x8 vv; } aue, auo;
      {
        float4 x0 = *(const float4*)(xr + ke);
        float4 x1 = *(const float4*)(xr + ke + 4);
        float4 s0 = *(const float4*)(smooth + ke);
        float4 s1 = *(const float4*)(smooth + ke + 4);
        v[0] = x0.x * s0.x; v[1] = x0.y * s0.y; v[2] = x0.z * s0.z; v[3] = x0.w * s0.w;
        v[4] = x1.x * s1.x; v[5] = x1.y * s1.y; v[6] = x1.z * s1.z; v[7] = x1.w * s1.w;
      }
      {
        float4 x0 = *(const float4*)(xr + ko);
        float4 x1 = *(const float4*)(xr + ko + 4);
        float4 s0 = *(const float4*)(smooth + ko);
        float4 s1 = *(const float4*)(smooth + ko + 4);
        v[8]  = x0.x * s0.x; v[9]  = x0.y * s0.y; v[10] = x0.z * s0.z; v[11] = x0.w * s0.w;
        v[12] = x1.x * s1.x; v[13] = x1.y * s1.y; v[14] = x1.z * s1.z; v[15] = x1.w * s1.w;
      }
#pragma unroll
      for (int i = 0; i < 8; ++i) {
        aue.h[i] = __float2bfloat16(v[i]);
        auo.h[i] = __float2bfloat16(v[8 + i]);
      }

      // lora MFMA (xs in bf16, both col tiles, both k-steps)
      acc0 = __builtin_amdgcn_mfma_f32_16x16x32_bf16(aue.vv, *(const bf16x8*)(br0 + ke), acc0, 0, 0, 0);
      acc1 = __builtin_amdgcn_mfma_f32_16x16x32_bf16(aue.vv, *(const bf16x8*)(br1 + ke), acc1, 0, 0, 0);
      acc0 = __builtin_amdgcn_mfma_f32_16x16x32_bf16(auo.vv, *(const bf16x8*)(br0 + ko), acc0, 0, 0, 0);
      acc1 = __builtin_amdgcn_mfma_f32_16x16x32_bf16(auo.vv, *(const bf16x8*)(br1 + ko), acc1, 0, 0, 0);

      // quantization of this group (lanes {r,r+16,r+32,r+48} x 16 elems)
      float am = 0.f;
#pragma unroll
      for (int i = 0; i < 16; ++i) am = fmaxf(am, fabsf(v[i]));
      am = fmaxf(am, __shfl_xor(am, 16));
      am = fmaxf(am, __shfl_xor(am, 32));
      const float scale = fmaxf(am / QMAXF, 1e-8f);

      alignas(16) bf16_t o[16];
#pragma unroll
      for (int i = 0; i < 16; ++i) {
        float q = rintf(v[i] / scale);     // IEEE div + round-half-even = jnp
        q = fminf(fmaxf(q, -8.f), 7.f);
        o[i] = __float2bfloat16(q * scale);
      }
      *(uint4*)(Ap + (size_t)mrow * KPAD + ke) = ((const uint4*)o)[0];
      *(uint4*)(Ap + (size_t)mrow * KPAD + ko) = ((const uint4*)o)[1];
    }

    // ---- cross-wave t reduction: C/D col=lane&15, row=(lane>>4)*4+q ----
    if (w != 0) {
#pragma unroll
      for (int q = 0; q < 4; ++q) {
        tpart[w - 1][kg * 4 + q][r]      = acc0[q];
        tpart[w - 1][kg * 4 + q][16 + r] = acc1[q];
      }
    }
    __syncthreads();
    if (w == 0) {
#pragma unroll
      for (int q = 0; q < 4; ++q) {
        const int orow = m0 + kg * 4 + q;
        float s0 = acc0[q], s1 = acc1[q];
#pragma unroll
        for (int j = 0; j < 3; ++j) {
          s0 += tpart[j][kg * 4 + q][r];
          s1 += tpart[j][kg * 4 + q][16 + r];
        }
        Ap[(size_t)orow * KPAD + 4096 + r]      = __float2bfloat16(s0);
        Ap[(size_t)orow * KPAD + 4096 + 16 + r] = __float2bfloat16(s1);
      }
      // zero pad cols 4128..4159
      alignas(16) bf16_t z[8] = {};
      *(uint4*)(Ap + (size_t)mrow * KPAD + 4128 + kg * 8) = *(const uint4*)z;
    }

  } else {                                 // ---- quant_w ----
    const int row = bid - 512;
    const int k0  = tid * 16;
    const float* wr = w + (size_t)row * K_DIM + k0;

    float v[16];
#pragma unroll
    for (int i = 0; i < 4; ++i) {
      float4 wv = *(const float4*)(wr + i * 4);
      v[i*4+0] = wv.x; v[i*4+1] = wv.y; v[i*4+2] = wv.z; v[i*4+3] = wv.w;
    }
    float am = 0.f;
#pragma unroll
    for (int i = 0; i < 16; ++i) am = fmaxf(am, fabsf(v[i]));
    am = fmaxf(am, __shfl_xor(am, 1));
    am = fmaxf(am, __shfl_xor(am, 2));
    const float scale = fmaxf(am / QMAXF, 1e-8f);

    alignas(16) bf16_t o[16];
#pragma unroll
    for (int i = 0; i < 16; ++i) {
      float q = rintf(v[i] / scale);
      q = fminf(fmaxf(q, -8.f), 7.f);
      o[i] = __float2bfloat16(q * scale);
    }
    bf16_t* dst = Bp + (size_t)row * KPAD + k0;
    ((uint4*)dst)[0] = ((uint4*)o)[0];
    ((uint4*)dst)[1] = ((uint4*)o)[1];
    if (tid < 32) {
      Bp[(size_t)row * KPAD + 4096 + tid] = __float2bfloat16(lora_up[row * R_DIM + tid]);
    } else if (tid < 64) {
      Bp[(size_t)row * KPAD + 4096 + tid] = __float2bfloat16(0.f);
    }
  }
}

// ---------------------------------------------------------------------------
// 256x256x64 8-phase GEMM, 4 barriers/ktile (round-16 champion, unchanged).
// WAR audit: bar1 (Ph2 stage vs LOAD_BN reads), bar2 (Ph4 stage vs q1 reads),
// bar4a (MANDATORY vmcnt publication), bar4b (Ph1 stage vs q2/q3 reads).
// vmcnt ring: at Ph4(u) queue = 14, retire 8 = all of ktile u+1.
// A quadrant-major LDS (lds_row = q*64 + wm*32 + r).  Swizzle: 16B granule
// ^= (row&7) on stage-source and ds_read (measured 0 conflicts).
// Measured: 231 us = 1207 TF, MfmaUtil 55.3%.  Structural floor of this
// template: LDS-read(2313cyc) + MFMA(2048cyc) serialize per ktile.
// ---------------------------------------------------------------------------
__global__ __launch_bounds__(512, 2) void gemm_kernel(
    const bf16_t* __restrict__ A, const bf16_t* __restrict__ B,
    const float* __restrict__ bias, float* __restrict__ C) {
  extern __shared__ __align__(16) bf16_t lds[];   // 65536 elems = 128 KiB

  // XCD-aware swizzle: nwg = 512, divisible by 8
  const int wg  = blockIdx.x;
  const int swz = (wg & 7) * 64 + (wg >> 3);
  const int bn  = swz & 15;    // 0..15
  const int bm  = swz >> 4;    // 0..31

  const int tid  = threadIdx.x;
  const int lane = tid & 63;
  const int wid  = tid >> 6;     // 0..7
  const int wm   = wid >> 2;     // 0..1
  const int wn   = wid & 3;      // 0..3

  const int lr = lane & 15;      // frag row within 16
  const int lg = lane >> 4;      // k-granule subindex 0..3
  const int l7 = lane & 7;
  const int gk0 = ((0 + lg) ^ l7) * 8;   // swizzled elem offset, k-half 0
  const int gk1 = ((4 + lg) ^ l7) * 8;   // k-half 1

  // staging geometry
  const int sr   = tid >> 3;                 // 0..63
  const int sl   = tid & 7;                  // granule slot
  const int gcol = (sl ^ (sr & 7)) * 8;      // inverse-swizzled source col
  const bf16_t* Abase = A + (size_t)(bm * 256 + ((sr >> 5) & 1) * 128 + (sr & 31)) * KPAD + gcol;
  const bf16_t* Bbase = B + (size_t)(bn * 256 + sr) * KPAD + gcol;
  bf16_t* ldsb = lds;

#define STAGE_A(buf, h, kt) do {                                               \
    stage16(Abase + (size_t)((h) * 2 + 0) * 32 * KPAD + (kt) * 64,             \
            ldsb + (buf) * 32768 + (h) * 8192 + 0 * 4096 + tid * 8);           \
    stage16(Abase + (size_t)((h) * 2 + 1) * 32 * KPAD + (kt) * 64,             \
            ldsb + (buf) * 32768 + (h) * 8192 + 1 * 4096 + tid * 8);           \
  } while (0)
#define STAGE_B(buf, h, kt) do {                                               \
    stage16(Bbase + (size_t)((h) * 128 + 0) * KPAD + (kt) * 64,                \
            ldsb + (buf) * 32768 + 16384 + (h) * 8192 + 0 * 4096 + tid * 8);   \
    stage16(Bbase + (size_t)((h) * 128 + 64) * KPAD + (kt) * 64,               \
            ldsb + (buf) * 32768 + 16384 + (h) * 8192 + 1 * 4096 + tid * 8);   \
  } while (0)

  f32x4  acc[8][4] = {};
  bf16x8 aA[2][2];   // A-frag ping (quadrants 0,2)
  bf16x8 aB[2][2];   // A-frag pong (quadrants 1,3)
  bf16x8 bF[4][2];   // B-frags, one set, reloaded per ktile

#define LOAD_A(DST, q, cb) do {                                                \
    const bf16_t* pa_ = ldsb + (cb) * 32768 + ((q) * 64 + wm * 32 + lr) * 64;  \
    DST[0][0] = *(const bf16x8*)(pa_ + gk0);                                   \
    DST[0][1] = *(const bf16x8*)(pa_ + gk1);                                   \
    DST[1][0] = *(const bf16x8*)(pa_ + 1024 + gk0);                            \
    DST[1][1] = *(const bf16x8*)(pa_ + 1024 + gk1);                            \
  } while (0)
#define LOAD_BN(nbuf) do {                                                     \
    _Pragma("unroll")                                                          \
    for (int j = 0; j < 4; ++j) {                                              \
      const bf16_t* pb_ = ldsb + (nbuf) * 32768 + 16384 + (wn * 64 + j * 16 + lr) * 64; \
      bF[j][0] = *(const bf16x8*)(pb_ + gk0);                                  \
      bF[j][1] = *(const bf16x8*)(pb_ + gk1);                                  \
    }                                                                          \
  } while (0)
#define MFMA_Q(q, AARR) do {                                                   \
    _Pragma("unroll")                                                          \
    for (int i = 0; i < 2; ++i)                                                \
      _Pragma("unroll")                                                        \
      for (int j = 0; j < 4; ++j) {                                            \
        acc[(q)*2+i][j] = __builtin_amdgcn_mfma_f32_16x16x32_bf16(             \
            AARR[i][0], bF[j][0], acc[(q)*2+i][j], 0, 0, 0);                   \
        acc[(q)*2+i][j] = __builtin_amdgcn_mfma_f32_16x16x32_bf16(             \
            AARR[i][1], bF[j][1], acc[(q)*2+i][j], 0, 0, 0);                   \
      }                                                                        \
  } while (0)

#define KTILE(u, cur) do {                                                     \
    /* ---- Ph1: stage A2(u+1); drain P4-tail reads; MFMA q0 ---- */           \
    if ((u) + 1 < NT) STAGE_A((cur) ^ 1, 1, (u) + 1);                          \
    asm volatile("s_waitcnt lgkmcnt(0)" ::: "memory");                         \
    __builtin_amdgcn_sched_barrier(0);                                         \
    LOAD_A(aB, 1, cur);                                                        \
    __builtin_amdgcn_sched_barrier(0);                                         \
    __builtin_amdgcn_s_setprio(1);                                             \
    MFMA_Q(0, aA);                                                             \
    __builtin_amdgcn_s_setprio(0);                                             \
    __builtin_amdgcn_s_barrier();                     /* bar1 */               \
    /* ---- Ph2: stage B1(u+2); MFMA q1 ---- */                                \
    if ((u) + 2 < NT) STAGE_B(cur, 0, (u) + 2);                                \
    asm volatile("s_waitcnt lgkmcnt(0)" ::: "memory");                         \
    __builtin_amdgcn_sched_barrier(0);                                         \
    LOAD_A(aA, 2, cur);                                                        \
    __builtin_amdgcn_sched_barrier(0);                                         \
    __builtin_amdgcn_s_setprio(1);                                             \
    MFMA_Q(1, aB);                                                             \
    __builtin_amdgcn_s_setprio(0);                                             \
    __builtin_amdgcn_s_barrier();                     /* bar2 */               \
    /* ---- Ph3: stage B2(u+2); MFMA q2 (no close barrier) ---- */             \
    if ((u) + 2 < NT) STAGE_B(cur, 1, (u) + 2);                                \
    asm volatile("s_waitcnt lgkmcnt(0)" ::: "memory");                         \
    __builtin_amdgcn_sched_barrier(0);                                         \
    LOAD_A(aB, 3, cur);                                                        \
    __builtin_amdgcn_sched_barrier(0);                                         \
    __builtin_amdgcn_s_setprio(1);                                             \
    MFMA_Q(2, aA);                                                             \
    __builtin_amdgcn_s_setprio(0);                                             \
    /* ---- Ph4: stage A1(u+2); counted wait; MANDATORY barrier; MFMA q3 */    \
    if ((u) + 2 < NT) {                                                        \
      STAGE_A(cur, 0, (u) + 2);                                                \
      asm volatile("s_waitcnt vmcnt(6)" ::: "memory");                         \
    } else {                                                                   \
      asm volatile("s_waitcnt vmcnt(0)" ::: "memory");                         \
    }                                                                          \
    __builtin_amdgcn_s_barrier();                     /* bar4a (vmcnt) */      \
    asm volatile("s_waitcnt lgkmcnt(0)" ::: "memory");                         \
    __builtin_amdgcn_sched_barrier(0);                                         \
    if ((u) + 1 < NT) LOAD_A(aA, 0, (cur) ^ 1);                                \
    __builtin_amdgcn_sched_barrier(0);                                         \
    __builtin_amdgcn_s_setprio(1);                                             \
    MFMA_Q(3, aB);                                                             \
    __builtin_amdgcn_s_setprio(0);                                             \
    __builtin_amdgcn_sched_barrier(0);                                         \
    if ((u) + 1 < NT) LOAD_BN((cur) ^ 1);                                      \
    __builtin_amdgcn_s_barrier();                     /* bar4b */              \
  } while (0)

  // ---- prologue: stage ktile0 fully + ktile1's B1,B2,A1; wait ktile0;
  //      preload B(0) and A-q0(0) fragment registers ----
  STAGE_B(0, 0, 0); STAGE_B(0, 1, 0); STAGE_A(0, 0, 0); STAGE_A(0, 1, 0);
  STAGE_B(1, 0, 1); STAGE_B(1, 1, 1); STAGE_A(1, 0, 1);
  asm volatile("s_waitcnt vmcnt(6)" ::: "memory");
  __builtin_amdgcn_s_barrier();
  LOAD_BN(0);
  LOAD_A(aA, 0, 0);

  for (int base = 0; base < 64; base += 2) {
    KTILE(base,     0);
    KTILE(base + 1, 1);
  }
  KTILE(64, 0);

  // ---- epilogue: C/D layout col = lane&15, row = (lane>>4)*4 + e ----
  const int colb = bn * 256 + wn * 64 + lr;
  const int rowb = bm * 256 + wm * 128 + lg * 4;
#pragma unroll
  for (int j = 0; j < 4; ++j) {
    const int gc = colb + j * 16;
    const float bv = bias[gc];
#pragma unroll
    for (int q = 0; q < 4; ++q)
#pragma unroll
      for (int i = 0; i < 2; ++i) {
        const int gr = rowb + q * 32 + i * 16;
#pragma unroll
        for (int e = 0; e < 4; ++e)
          C[(size_t)(gr + e) * N_DIM + gc] = acc[q * 2 + i][j][e] + bv;
      }
  }
#undef STAGE_A
#undef STAGE_B
#undef LOAD_A
#undef LOAD_BN
#undef MFMA_Q
#undef KTILE
}

// ---------------------------------------------------------------------------
extern "C" void kernel_launch(void* const* d_in, const int* in_sizes, int n_in,
                              void* d_out, int out_size, void* d_ws, size_t ws_size,
                              hipStream_t stream) {
  const float* x         = (const float*)d_in[0];
  const float* w_res     = (const float*)d_in[1];
  const float* lora_down = (const float*)d_in[2];
  const float* lora_up   = (const float*)d_in[3];
  const float* smooth    = (const float*)d_in[4];
  const float* b         = (const float*)d_in[5];
  float* out = (float*)d_out;

  // workspace: Ap [M][KPAD] bf16 (68.2 MB), Bp [N][KPAD] bf16 (34.1 MB),
  // ldT [R][K] bf16 (256 KB)
  bf16_t* Ap  = (bf16_t*)d_ws;
  bf16_t* Bp  = Ap + (size_t)M_DIM * KPAD;
  bf16_t* ldT = Bp + (size_t)N_DIM * KPAD;

  // allow 128 KiB dynamic LDS (idempotent, host-side, capture-safe)
  hipFuncSetAttribute((const void*)gemm_kernel,
                      hipFuncAttributeMaxDynamicSharedMemorySize, 131072);

  ldT_kernel<<<K_DIM / 256, 256, 0, stream>>>(lora_down, ldT);
  prep_all_kernel<<<512 + N_DIM, 256, 0, stream>>>(
      x, smooth, w_res, lora_up, ldT, Ap, Bp);
  gemm_kernel<<<(M_DIM / 256) * (N_DIM / 256), 512, 131072, stream>>>(Ap, Bp, b, out);
}